// Round 1
// 367.785 us; speedup vs baseline: 1.1882x; 1.1882x over previous
//
#include <hip/hip_runtime.h>
#include <cmath>

#define NB 8
#define NS 32
#define NP 8
#define NV 8000
#define ND 128
#define CONC 5.0f
#define EPS 1e-8f

#define NBS (NB * NS)      // 256 (b,s) rows
#define TROWS 8            // bs-rows per k_B tile (dense, no compaction)
#define USPLIT 25          // u-dimension splits: 8000 = 25*320
#define URANGE 320
#define UCHUNK 64
#define NCHUNK (URANGE / UCHUNK)   // 5
#define ST 12              // padded LDS stride (8 rows + 4 pad) -> conflict-free b128
#define MAXIDX (NB * NS * NP)      // 2048

// ---- workspace layout (4-byte units) ----
#define WS_SCALE  0        // float[2048]   (indexed by idx = bs*NP+p)
#define WS_CN     2048     // float[1024]
#define WS_COS    3072     // float[64000]
#define WS_MEANJ  67072    // float[32768]
#define WS_P      99840    // float[2048*8000] = 65.5 MB (indexed by idx)

// ---------------------------------------------------------------------------
// k_mean: per (b,s) ragged mean over P; also zeroes out[].
// grid=NB*NS (256), block=ND (128): out has exactly 256*128 elements.
// ---------------------------------------------------------------------------
__global__ void k_mean(const int* __restrict__ concepts,
                       const int* __restrict__ concepts_length,
                       const float* __restrict__ embed_w,
                       float* __restrict__ mean_j,
                       float* __restrict__ out) {
    const int bs = blockIdx.x;
    const int d = threadIdx.x;
    out[bs * ND + d] = 0.0f;
    const int len = concepts_length[bs];
    float sum = 0.0f;
    for (int p = 0; p < len; ++p) {
        const int c = concepts[bs * NP + p];
        sum += embed_w[(size_t)c * ND + d];
    }
    mean_j[(size_t)bs * ND + d] = sum / (float)(len > 0 ? len : 1);
}

// ---------------------------------------------------------------------------
// k_ctx2: per b, mean over valid segments + normalize.  grid=NB, block=ND
// ---------------------------------------------------------------------------
__global__ void k_ctx2(const int* __restrict__ seg_len,
                       const float* __restrict__ mean_j,
                       float* __restrict__ cn) {
    const int b = blockIdx.x;
    const int d = threadIdx.x;
    const int sl = seg_len[b];
    float acc = 0.0f;
    for (int s = 0; s < sl; ++s) acc += mean_j[(size_t)(b * NS + s) * ND + d];
    acc /= (float)sl;
    float ss = acc * acc;
    #pragma unroll
    for (int m = 1; m < 64; m <<= 1) ss += __shfl_xor(ss, m);
    __shared__ float sred[2];
    if ((d & 63) == 0) sred[d >> 6] = ss;
    __syncthreads();
    const float tot = sred[0] + sred[1];
    cn[b * ND + d] = acc / fmaxf(sqrtf(tot), EPS);
}

// ---------------------------------------------------------------------------
// k_cos: cos[b][v] = |cn[b] . normalize(kb[v])|.  grid=NV/8, block=256
// ---------------------------------------------------------------------------
__global__ __launch_bounds__(256) void k_cos(const float* __restrict__ kb,
                                             const float* __restrict__ cn,
                                             float* __restrict__ cos_bv) {
    __shared__ float s_cn[NB * ND];
    const int t = threadIdx.x;
    for (int i = t; i < NB * ND; i += 256) s_cn[i] = cn[i];
    __syncthreads();

    const int v = blockIdx.x * 8 + (t >> 5);
    const int l = t & 31;
    const float4 kv = *reinterpret_cast<const float4*>(kb + (size_t)v * ND + (l << 2));
    float ss = kv.x * kv.x + kv.y * kv.y + kv.z * kv.z + kv.w * kv.w;
    #pragma unroll
    for (int m = 1; m < 32; m <<= 1) ss += __shfl_xor(ss, m);
    const float inv = 1.0f / fmaxf(sqrtf(ss), EPS);
    #pragma unroll
    for (int b = 0; b < NB; ++b) {
        const float4 cv = *reinterpret_cast<const float4*>(&s_cn[b * ND + (l << 2)]);
        float dot = kv.x * cv.x + kv.y * cv.y + kv.z * cv.z + kv.w * cv.w;
        #pragma unroll
        for (int m = 1; m < 32; m <<= 1) dot += __shfl_xor(dot, m);
        if (l == 0) cos_bv[b * NV + v] = fabsf(dot * inv);
    }
}

// ---------------------------------------------------------------------------
// k_A: per valid triple idx=(b,s,p): row min/max, then ONE fused pass computing
// p = exp(w) (w in [0,5] -> e^w <= ~150, f32-safe; the constant factor cancels
// in the softmax normalization), storing p to pbuf[idx][NV] (direct indexing,
// NO slot compaction) and recording f_scale[idx] = 1/(total*len).
// grid=2048, block=256.
// ---------------------------------------------------------------------------
__global__ __launch_bounds__(256) void k_A(
        const int* __restrict__ concepts,
        const int* __restrict__ concepts_length,
        const int* __restrict__ seg_len,
        const float* __restrict__ edge,
        const float* __restrict__ aff,
        const float* __restrict__ lam,
        const float* __restrict__ cos_bv,
        float* __restrict__ f_scale,
        float* __restrict__ pbuf) {
    const int idx = blockIdx.x;
    const int b = idx >> 8;
    const int s = (idx >> 3) & 31;
    const int p = idx & 7;
    if (s >= seg_len[b]) return;
    const int len = concepts_length[b * NS + s];
    if (p >= len) return;
    const int c = concepts[idx];

    const int t = threadIdx.x;
    const float* __restrict__ erow = edge + (size_t)c * NV;
    float4 ev[8];
    float lmax = -INFINITY, lmin = INFINITY;
    #pragma unroll
    for (int k = 0; k < 8; ++k) {
        const int f = t + (k << 8);            // float4 index, valid < 2000
        if (f < 2000) {
            const float4 e = *reinterpret_cast<const float4*>(erow + (f << 2));
            ev[k] = e;
            lmax = fmaxf(lmax, fmaxf(fmaxf(e.x, e.y), fmaxf(e.z, e.w)));
            lmin = fminf(lmin, fminf(fminf(e.x, e.y), fminf(e.z, e.w)));
        }
    }
    #pragma unroll
    for (int m = 1; m < 64; m <<= 1) {
        lmax = fmaxf(lmax, __shfl_xor(lmax, m));
        lmin = fminf(lmin, __shfl_xor(lmin, m));
    }
    __shared__ float s_mn[4], s_mx[4], s_sum[4];
    if ((t & 63) == 0) { s_mn[t >> 6] = lmin; s_mx[t >> 6] = lmax; }
    __syncthreads();
    const float rmin = fminf(fminf(s_mn[0], s_mn[1]), fminf(s_mn[2], s_mn[3]));
    const float rmax = fmaxf(fmaxf(s_mx[0], s_mx[1]), fmaxf(s_mx[2], s_mx[3]));
    const float rng = rmax - rmin;
    const float inv_rng = 1.0f / (rng + (rng == 0.0f ? 1.0f : 0.0f));

    // fused: w -> exp -> store -> sum
    const float* __restrict__ cosb = cos_bv + b * NV;
    float* __restrict__ prow = pbuf + (size_t)idx * NV;
    float lsum = 0.0f;
    #pragma unroll
    for (int k = 0; k < 8; ++k) {
        const int f = t + (k << 8);
        if (f < 2000) {
            const int u = f << 2;
            const float4 l4 = *reinterpret_cast<const float4*>(lam + u);
            const float4 a4 = *reinterpret_cast<const float4*>(aff + u);
            const float4 c4 = *reinterpret_cast<const float4*>(cosb + u);
            float4 e = ev[k];
            e.x *= inv_rng; e.y *= inv_rng; e.z *= inv_rng; e.w *= inv_rng;
            float4 pe;
            pe.x = __expf((l4.x * e.x * c4.x + (1.0f - l4.x) * ((e.x > 0.0f) ? 1.0f : 0.0f) * a4.x) * CONC);
            pe.y = __expf((l4.y * e.y * c4.y + (1.0f - l4.y) * ((e.y > 0.0f) ? 1.0f : 0.0f) * a4.y) * CONC);
            pe.z = __expf((l4.z * e.z * c4.z + (1.0f - l4.z) * ((e.z > 0.0f) ? 1.0f : 0.0f) * a4.z) * CONC);
            pe.w = __expf((l4.w * e.w * c4.w + (1.0f - l4.w) * ((e.w > 0.0f) ? 1.0f : 0.0f) * a4.w) * CONC);
            *reinterpret_cast<float4*>(prow + (f << 2)) = pe;
            lsum += pe.x + pe.y + pe.z + pe.w;
        }
    }
    #pragma unroll
    for (int m = 1; m < 64; m <<= 1) lsum += __shfl_xor(lsum, m);
    if ((t & 63) == 0) s_sum[t >> 6] = lsum;
    __syncthreads();
    if (t == 0) {
        const float total = s_sum[0] + s_sum[1] + s_sum[2] + s_sum[3];
        f_scale[idx] = 1.0f / (total * (float)len);
    }
}

// ---------------------------------------------------------------------------
// k_B: dense (b,s)-tiled GEMV. The p-dimension is folded DURING LDS staging:
// each staged value is sum_p f_scale[idx]*pbuf[idx][u] over p < len, so the
// FMA loop runs on 8 bs-rows (acc = 8 x float4 = 32 VGPR) instead of 16
// slot-rows. Wholly-invalid tiles skipped via seg_len; rows with len==0
// contribute exact zeros. Staging loads are predicated on p<len (pbuf rows
// for invalid (b,s,p) are poisoned, must not be read).
// grid=(NBS/TROWS=32, 25), block=256.
// ---------------------------------------------------------------------------
__global__ __launch_bounds__(256) void k_B(
        const float* __restrict__ kb,
        const int* __restrict__ seg_len,
        const int* __restrict__ concepts_length,
        const float* __restrict__ f_scale,
        const float* __restrict__ pbuf,
        float* __restrict__ out) {
    const int tile = blockIdx.x;               // 0..31
    const int bs0 = tile * TROWS;              // 8 consecutive bs rows, same b
    if ((bs0 & 31) >= seg_len[bs0 >> 5]) return;   // whole tile beyond seg_len

    const int t = threadIdx.x;
    const int ug = t & 7;          // u-group, lane bits 0-2
    const int l = t >> 3;          // d-quad 0..31

    __shared__ int   s_ln[TROWS];
    __shared__ float s_sc[TROWS * NP];
    __shared__ __align__(16) float s_p[UCHUNK * ST];   // 3 KB

    if (t < TROWS) {
        const int bs = bs0 + t;
        s_ln[t] = ((bs & 31) < seg_len[bs >> 5]) ? concepts_length[bs] : 0;
    }
    if (t < TROWS * NP) {
        const int bs = bs0 + (t >> 3);
        const int p = t & 7;
        const bool valid = ((bs & 31) < seg_len[bs >> 5]) && (p < concepts_length[bs]);
        s_sc[t] = valid ? f_scale[bs * NP + p] : 0.0f;
    }
    __syncthreads();

    const int srow = t >> 5;       // 0..7 bs-row for staging
    const int sq = t & 31;         // float2 within 64 u
    const int lenr = s_ln[srow];
    float scr[NP];
    #pragma unroll
    for (int p = 0; p < NP; ++p) scr[p] = s_sc[srow * NP + p];
    const float* __restrict__ pr = pbuf + (size_t)(bs0 + srow) * NP * NV + (sq << 1);
    const int u0 = blockIdx.y * URANGE;

    float4 acc[TROWS];
    #pragma unroll
    for (int j = 0; j < TROWS; ++j) acc[j] = make_float4(0.f, 0.f, 0.f, 0.f);

    // combined prefetch of chunk 0: sum_p scale*p over valid p
    float2 pv = make_float2(0.f, 0.f);
    #pragma unroll
    for (int p = 0; p < NP; ++p)
        if (p < lenr) {
            const float2 v = *reinterpret_cast<const float2*>(pr + (size_t)p * NV + u0);
            pv.x = fmaf(scr[p], v.x, pv.x);
            pv.y = fmaf(scr[p], v.y, pv.y);
        }

    for (int ch = 0; ch < NCHUNK; ++ch) {
        // stage combined row chunk: q[uu][row] at stride ST
        const int uu0 = sq << 1;
        s_p[(uu0 + 0) * ST + srow] = pv.x;
        s_p[(uu0 + 1) * ST + srow] = pv.y;
        // prefetch+combine chunk ch+1
        float2 pn = make_float2(0.f, 0.f);
        if (ch + 1 < NCHUNK) {
            const int off = u0 + (ch + 1) * UCHUNK;
            #pragma unroll
            for (int p = 0; p < NP; ++p)
                if (p < lenr) {
                    const float2 v = *reinterpret_cast<const float2*>(pr + (size_t)p * NV + off);
                    pn.x = fmaf(scr[p], v.x, pn.x);
                    pn.y = fmaf(scr[p], v.y, pn.y);
                }
        }
        __syncthreads();

        const int uc = u0 + ch * UCHUNK;
        #pragma unroll
        for (int r = 0; r < 8; ++r) {
            const int uu = ug + (r << 3);
            const float4 kv = *reinterpret_cast<const float4*>(
                kb + (size_t)(uc + uu) * ND + (l << 2));
            const float4 p0 = *reinterpret_cast<const float4*>(&s_p[uu * ST]);     // rows 0-3
            const float4 p1 = *reinterpret_cast<const float4*>(&s_p[uu * ST + 4]); // rows 4-7
            acc[0].x = fmaf(p0.x, kv.x, acc[0].x); acc[0].y = fmaf(p0.x, kv.y, acc[0].y);
            acc[0].z = fmaf(p0.x, kv.z, acc[0].z); acc[0].w = fmaf(p0.x, kv.w, acc[0].w);
            acc[1].x = fmaf(p0.y, kv.x, acc[1].x); acc[1].y = fmaf(p0.y, kv.y, acc[1].y);
            acc[1].z = fmaf(p0.y, kv.z, acc[1].z); acc[1].w = fmaf(p0.y, kv.w, acc[1].w);
            acc[2].x = fmaf(p0.z, kv.x, acc[2].x); acc[2].y = fmaf(p0.z, kv.y, acc[2].y);
            acc[2].z = fmaf(p0.z, kv.z, acc[2].z); acc[2].w = fmaf(p0.z, kv.w, acc[2].w);
            acc[3].x = fmaf(p0.w, kv.x, acc[3].x); acc[3].y = fmaf(p0.w, kv.y, acc[3].y);
            acc[3].z = fmaf(p0.w, kv.z, acc[3].z); acc[3].w = fmaf(p0.w, kv.w, acc[3].w);
            acc[4].x = fmaf(p1.x, kv.x, acc[4].x); acc[4].y = fmaf(p1.x, kv.y, acc[4].y);
            acc[4].z = fmaf(p1.x, kv.z, acc[4].z); acc[4].w = fmaf(p1.x, kv.w, acc[4].w);
            acc[5].x = fmaf(p1.y, kv.x, acc[5].x); acc[5].y = fmaf(p1.y, kv.y, acc[5].y);
            acc[5].z = fmaf(p1.y, kv.z, acc[5].z); acc[5].w = fmaf(p1.y, kv.w, acc[5].w);
            acc[6].x = fmaf(p1.z, kv.x, acc[6].x); acc[6].y = fmaf(p1.z, kv.y, acc[6].y);
            acc[6].z = fmaf(p1.z, kv.z, acc[6].z); acc[6].w = fmaf(p1.z, kv.w, acc[6].w);
            acc[7].x = fmaf(p1.w, kv.x, acc[7].x); acc[7].y = fmaf(p1.w, kv.y, acc[7].y);
            acc[7].z = fmaf(p1.w, kv.z, acc[7].z); acc[7].w = fmaf(p1.w, kv.w, acc[7].w);
        }
        __syncthreads();
        pv = pn;
    }

    // butterfly reduce over ug (lane bits 0-2); lane ug keeps row ug
    float4 r0 = make_float4(0.f, 0.f, 0.f, 0.f);
    #pragma unroll
    for (int j = 0; j < TROWS; ++j) {
        float4 a = acc[j];
        #pragma unroll
        for (int m = 1; m <= 4; m <<= 1) {
            a.x += __shfl_xor(a.x, m);
            a.y += __shfl_xor(a.y, m);
            a.z += __shfl_xor(a.z, m);
            a.w += __shfl_xor(a.w, m);
        }
        if (j == ug) r0 = a;
    }

    if (s_ln[ug] != 0) {           // scale already folded at staging
        float* o = out + (size_t)(bs0 + ug) * ND + (l << 2);
        atomicAdd(o + 0, r0.x);
        atomicAdd(o + 1, r0.y);
        atomicAdd(o + 2, r0.z);
        atomicAdd(o + 3, r0.w);
    }
}

extern "C" void kernel_launch(void* const* d_in, const int* in_sizes, int n_in,
                              void* d_out, int out_size, void* d_ws, size_t ws_size,
                              hipStream_t stream) {
    const int*   concepts        = (const int*)d_in[0];
    const int*   concepts_length = (const int*)d_in[1];
    const int*   seg_len         = (const int*)d_in[2];
    const float* embed_w         = (const float*)d_in[3];
    const float* embed_kb_w      = (const float*)d_in[4];
    const float* edge_matrix     = (const float*)d_in[5];
    const float* affectiveness   = (const float*)d_in[6];
    const float* lam             = (const float*)d_in[7];
    float* out = (float*)d_out;

    float* wsf = (float*)d_ws;
    float* f_scale  = wsf + WS_SCALE;
    float* cn       = wsf + WS_CN;
    float* cos_bv   = wsf + WS_COS;
    float* mean_j   = wsf + WS_MEANJ;
    float* pbuf     = wsf + WS_P;

    k_mean<<<NB * NS, ND, 0, stream>>>(concepts, concepts_length, embed_w,
                                       mean_j, out);
    k_ctx2<<<NB, ND, 0, stream>>>(seg_len, mean_j, cn);
    k_cos<<<NV / 8, 256, 0, stream>>>(embed_kb_w, cn, cos_bv);
    k_A<<<MAXIDX, 256, 0, stream>>>(concepts, concepts_length, seg_len,
                                    edge_matrix, affectiveness, lam, cos_bv,
                                    f_scale, pbuf);
    dim3 gB(NBS / TROWS, USPLIT, 1);
    k_B<<<gB, 256, 0, stream>>>(embed_kb_w, seg_len, concepts_length,
                                f_scale, pbuf, out);
}